// Round 10
// baseline (77.179 us; speedup 1.0000x reference)
//
#include <hip/hip_runtime.h>

// out[b] = 0.75 * sum_i x[b,i] * s[i],  s[i] = sum_h W[h,i]
// x: [2048, 8192] f32 ; W: [8192, 8192] f32 ; out: [2048] f32
//
// R9 structure (memset ; colsum ; rowdot). Single change vs R9:
// rowdot processes 4 rows/block with 512-thread blocks (512 blocks,
// 2 blocks/CU x 8 waves = 16 waves/CU — same occupancy as R9's rowdot2).
// Each s float4 feeds 4 FMA chains: s re-read traffic 32 MB -> 16 MB.

#define I_SIZE 8192
#define H_SIZE 8192
#define BATCH  2048
#define ROWS_PER_CHUNK 64

// ---- Kernel 1: panel colsum (R1 EXACT; ~45.5 us, request-rate-bound) ------
__global__ __launch_bounds__(256) void colsum_kernel(const float* __restrict__ W,
                                                     float* __restrict__ s) {
    const int col = blockIdx.x * 1024 + threadIdx.x * 4;
    const size_t r0 = (size_t)blockIdx.y * ROWS_PER_CHUNK;
    const float* base = W + r0 * I_SIZE + col;

    float4 acc = make_float4(0.f, 0.f, 0.f, 0.f);
#pragma unroll 8
    for (int r = 0; r < ROWS_PER_CHUNK; ++r) {
        float4 v = *reinterpret_cast<const float4*>(base + (size_t)r * I_SIZE);
        acc.x += v.x; acc.y += v.y; acc.z += v.z; acc.w += v.w;
    }
    atomicAdd(&s[col + 0], acc.x);
    atomicAdd(&s[col + 1], acc.y);
    atomicAdd(&s[col + 2], acc.z);
    atomicAdd(&s[col + 3], acc.w);
}

// ---- Kernel 2: rowdot, 4 rows/block, 512 threads --------------------------
__global__ __launch_bounds__(512) void rowdot4_kernel(const float* __restrict__ x,
                                                      const float* __restrict__ s,
                                                      float* __restrict__ out) {
    const int t = threadIdx.x;            // 0..511
    const int r0 = blockIdx.x * 4;
    const float* x0 = x + (size_t)r0 * I_SIZE;
    const float* x1 = x0 + I_SIZE;
    const float* x2 = x1 + I_SIZE;
    const float* x3 = x2 + I_SIZE;

    float a0 = 0.f, a1 = 0.f, a2 = 0.f, a3 = 0.f;
#pragma unroll
    for (int j = 0; j < 4; ++j) {
        const int i = t * 4 + j * 2048;   // 512 thr * 4 floats = 2048/iter
        const float4 sv = *reinterpret_cast<const float4*>(s + i);
        const float4 v0 = *reinterpret_cast<const float4*>(x0 + i);
        const float4 v1 = *reinterpret_cast<const float4*>(x1 + i);
        const float4 v2 = *reinterpret_cast<const float4*>(x2 + i);
        const float4 v3 = *reinterpret_cast<const float4*>(x3 + i);
        a0 += v0.x * sv.x + v0.y * sv.y + v0.z * sv.z + v0.w * sv.w;
        a1 += v1.x * sv.x + v1.y * sv.y + v1.z * sv.z + v1.w * sv.w;
        a2 += v2.x * sv.x + v2.y * sv.y + v2.z * sv.z + v2.w * sv.w;
        a3 += v3.x * sv.x + v3.y * sv.y + v3.z * sv.z + v3.w * sv.w;
    }

#pragma unroll
    for (int off = 32; off; off >>= 1) {
        a0 += __shfl_down(a0, off, 64);
        a1 += __shfl_down(a1, off, 64);
        a2 += __shfl_down(a2, off, 64);
        a3 += __shfl_down(a3, off, 64);
    }

    __shared__ float p[8][4];             // [wave][row]
    const int lane = t & 63, wid = t >> 6;
    if (lane == 0) { p[wid][0] = a0; p[wid][1] = a1; p[wid][2] = a2; p[wid][3] = a3; }
    __syncthreads();
    if (t < 4) {
        float r = 0.f;
#pragma unroll
        for (int w = 0; w < 8; ++w) r += p[w][t];
        out[r0 + t] = 0.75f * r;
    }
}

extern "C" void kernel_launch(void* const* d_in, const int* in_sizes, int n_in,
                              void* d_out, int out_size, void* d_ws, size_t ws_size,
                              hipStream_t stream) {
    const float* x = (const float*)d_in[0];   // [BATCH, I_SIZE]
    const float* W = (const float*)d_in[1];   // [H_SIZE, I_SIZE]
    float* out = (float*)d_out;               // [BATCH]
    float* s   = (float*)d_ws;                // [I_SIZE]

    hipMemsetAsync(s, 0, I_SIZE * sizeof(float), stream);

    dim3 grid1(I_SIZE / 1024, H_SIZE / ROWS_PER_CHUNK);
    colsum_kernel<<<grid1, 256, 0, stream>>>(W, s);
    rowdot4_kernel<<<BATCH / 4, 512, 0, stream>>>(x, s, out);
}